// Round 9
// baseline (573.411 us; speedup 1.0000x reference)
//
#include <hip/hip_runtime.h>

constexpr int N     = 3072;
constexpr int S     = 32;
constexpr int E     = 4;
constexpr int FIN   = 64;
constexpr int CAP   = 64;     // max sources per (e,n); Binomial(3072,0.005) mean 15.4, P(>=64)~1e-19
constexpr int NNi   = N * N;  // 9,437,184
constexpr int DUMMY = N;      // extra all-zero h row for gather padding
constexpr int BLK   = 256;    // 1 block/CU
constexpr int TPB   = 384;    // 6 waves x 2 nodes/wave = 12 nodes/block; 256*12 = 3072
constexpr int NPB   = 12;

__device__ __forceinline__ float rl(float v, int lane) {   // wave-uniform broadcast via VALU
    return __int_as_float(__builtin_amdgcn_readlane(__float_as_int(v), lane));
}
__device__ __forceinline__ float fast_sigmoid(float x) {
    x = fminf(fmaxf(x, -30.f), 30.f);
    return 1.f / (1.f + __expf(-x));
}
__device__ __forceinline__ float fast_tanh(float x) {
    x = fminf(fmaxf(x, -15.f), 15.f);
    float e = __expf(2.f * x);
    return (e - 1.f) / (e + 1.f);
}

// Cache-bypassing accessors: relaxed AGENT-scope atomics are coherent at the
// memory-side Infinity Cache (above the non-coherent per-XCD L2s).
__device__ __forceinline__ float ld_dev(const float* p) {
    return __hip_atomic_load((float*)p, __ATOMIC_RELAXED, __HIP_MEMORY_SCOPE_AGENT);
}
__device__ __forceinline__ void st_dev(float* p, float v) {
    __hip_atomic_store(p, v, __ATOMIC_RELAXED, __HIP_MEMORY_SCOPE_AGENT);
}

// Two-level monotone tree barrier (reset-free), 16 groups x 16 blocks.
__device__ __forceinline__ void gbar(int* bar, int ph, int b) {
    __syncthreads();          // compiler drains vmcnt(0) before s_barrier
    if (threadIdx.x == 0) {
        int* grp  = bar + (b >> 4) * 16;
        int* root = bar + 256;
        int* go   = bar + 272;
        int old = __hip_atomic_fetch_add(grp, 1, __ATOMIC_RELAXED, __HIP_MEMORY_SCOPE_AGENT);
        if (old + 1 == ph * 16) {
            int old2 = __hip_atomic_fetch_add(root, 1, __ATOMIC_RELAXED, __HIP_MEMORY_SCOPE_AGENT);
            if (old2 + 1 == ph * 16)
                __hip_atomic_store(go, ph, __ATOMIC_RELAXED, __HIP_MEMORY_SCOPE_AGENT);
        }
        int spins = 0;
        while (__hip_atomic_load(go, __ATOMIC_RELAXED, __HIP_MEMORY_SCOPE_AGENT) < ph) {
            __builtin_amdgcn_s_sleep(2);
            if (++spins > 300000) break;           // wedge -> terminate, not hang
        }
    }
    __syncthreads();
}

// ---------------------------------------------------------------------------
// Pass 1 (separate dispatch; inter-dispatch flush makes results coherent):
// dense fp32 adjacency -> CSR (per (e, target n): list of sources m).
// ---------------------------------------------------------------------------
__global__ __launch_bounds__(256) void build_csr(const float* __restrict__ edges,
                                                 int* __restrict__ deg,
                                                 int* __restrict__ csr) {
    int t = blockIdx.x * 256 + threadIdx.x;
    int idx4 = t * 4;
    float4 v = *reinterpret_cast<const float4*>(edges + idx4);
    if (v.x == 0.f && v.y == 0.f && v.z == 0.f && v.w == 0.f) return;
    int e   = idx4 / NNi;
    int rem = idx4 - e * NNi;
    int m   = rem / N;
    int nb  = rem - m * N;
    float w[4] = {v.x, v.y, v.z, v.w};
    int base = e * N + nb;
    #pragma unroll
    for (int j = 0; j < 4; ++j) {
        if (w[j] != 0.f) {
            int slot = base + j;
            int pos = atomicAdd(&deg[slot], 1);
            if (pos < CAP) csr[slot * CAP + pos] = m;
        }
    }
}

struct Params {
    const float *x, *fcw, *fcb;
    const float *wz, *wr, *wh, *uz, *ur, *uh, *bz, *br;
    const float *ow, *ob;
    const int   *deg, *csr;
    int   *bar;
    float *h0, *h1, *out;
};

// One gate pre-activation: sum_e act[e]·W[e][:, s] + hvec·U[:, s] + bias.
// W from LDS (wave-shared columns: 32 unique addrs/instr = broadcast-friendly),
// U from global (L1-hot), act/hvec from per-wave LDS scratch (float4 broadcast).
__device__ __forceinline__ float matvec(const float* __restrict__ Wg,
                                        const float* __restrict__ Ug,
                                        const float* __restrict__ actw,
                                        const float* __restrict__ hw,
                                        float bias, int s) {
    float acc = bias, acc2 = 0.f;
    #pragma unroll
    for (int e = 0; e < E; ++e) {
        const float* wc = Wg + e * 1024 + s;
        const float* ar = actw + e * 32;
        #pragma unroll
        for (int k4 = 0; k4 < 8; ++k4) {
            float4 a = *reinterpret_cast<const float4*>(ar + k4 * 4);
            acc  = fmaf(a.x, wc[(k4 * 4 + 0) * 32], acc);
            acc2 = fmaf(a.y, wc[(k4 * 4 + 1) * 32], acc2);
            acc  = fmaf(a.z, wc[(k4 * 4 + 2) * 32], acc);
            acc2 = fmaf(a.w, wc[(k4 * 4 + 3) * 32], acc2);
        }
    }
    const float* uc = Ug + s;
    #pragma unroll
    for (int k4 = 0; k4 < 8; ++k4) {
        float4 hv = *reinterpret_cast<const float4*>(hw + k4 * 4);
        acc  = fmaf(hv.x, uc[(k4 * 4 + 0) * 32], acc);
        acc2 = fmaf(hv.y, uc[(k4 * 4 + 1) * 32], acc2);
        acc  = fmaf(hv.z, uc[(k4 * 4 + 2) * 32], acc);
        acc2 = fmaf(hv.w, uc[(k4 * 4 + 3) * 32], acc2);
    }
    return acc + acc2;
}

// ---------------------------------------------------------------------------
// Fused cooperative kernel, 2 nodes per wave. Lane = (p, s); half p owns node
// b*12 + w*2 + p across all 4 edge types. Gates sequential (z, r, hh); act/h/rh
// round-trip per-wave LDS scratch so weight reads are wave-shared (halves the
// LDS bytes/node) and no readlane broadcasts or redundant hh remain.
// LDS: W 48K + scratch 9.2K = 57.4 KB. hval carried in-register all 15 iters.
// ---------------------------------------------------------------------------
__global__ __launch_bounds__(TPB, 1) void fused_ggnn(Params p) {
    __shared__ __align__(16) float sW[3 * 4096];     // [z|r|h][e][k][s] k-major
    __shared__ __align__(16) float sAct[6][2][E][32];// [wave][p][e][k]
    __shared__ __align__(16) float sH[6][2][32];     // h broadcast scratch
    __shared__ __align__(16) float sRH[6][2][32];    // r*h broadcast scratch

    const int tid  = threadIdx.x;
    const int b    = blockIdx.x;
    const int w    = tid >> 6;
    const int lane = tid & 63;
    const int pp   = lane >> 5;                      // which node of the pair
    const int s    = lane & 31;
    const int n    = b * NPB + w * 2 + pp;

    // ---- init: h0 = x @ fc_w + fc_b. Thread (n,s) mapping == wave mapping,
    // so hval stays in-register for the whole kernel.
    float hval;
    {
        float acc = p.fcb[s];
        #pragma unroll 8
        for (int k = 0; k < FIN; ++k)
            acc = fmaf(p.x[n * FIN + k], p.fcw[k * S + s], acc);
        hval = acc;
        st_dev(&p.h0[n * S + s], acc);
    }
    if (b == 0) {                                    // zero dummy rows, both buffers
        if (tid < 32)      st_dev(&p.h0[DUMMY * S + tid], 0.f);
        else if (tid < 64) st_dev(&p.h1[DUMMY * S + (tid - 32)], 0.f);
    }

    // ---- iteration-invariant CSR state: all 4 lists of my node
    int d[E]; const int* lst[E]; int dmx = 0;
    #pragma unroll
    for (int e = 0; e < E; ++e) {
        int sl = e * N + n;
        d[e]   = min(p.deg[sl], CAP);
        lst[e] = p.csr + sl * CAP;
        dmx    = max(dmx, d[e]);
    }

    const float* hp = p.h0;
    float*       hn = p.h1;
    int phase = 1;
    gbar(p.bar, phase, b); phase++;                  // h0 device-visible

    for (int l = 0; l < 3; ++l) {
        __syncthreads();                             // guard LDS reuse across layers
        {
            float4* dw = (float4*)sW;
            const float4* gz = (const float4*)(p.wz + l * 4096);
            const float4* gr = (const float4*)(p.wr + l * 4096);
            const float4* gh = (const float4*)(p.wh + l * 4096);
            for (int i = tid; i < 1024; i += TPB) {
                dw[i] = gz[i]; dw[1024 + i] = gr[i]; dw[2048 + i] = gh[i];
            }
        }
        __syncthreads();

        const float* Uz = p.uz + l * 1024;
        const float* Ur = p.ur + l * 1024;
        const float* Uh = p.uh + l * 1024;
        const float  bzv = p.bz[l * 32 + s];
        const float  brv = p.br[l * 32 + s];

        for (int it = 0; it < 5; ++it) {
            // ---- phase A: sparse gather, 4 lists interleaved (8 loads in flight)
            float a0 = 0.f, a1 = 0.f, a2 = 0.f, a3 = 0.f;
            for (int c = 0; c < dmx; c += 2) {
                int i00 = (c     < d[0]) ? lst[0][c]     : DUMMY;
                int i01 = (c + 1 < d[0]) ? lst[0][c + 1] : DUMMY;
                int i10 = (c     < d[1]) ? lst[1][c]     : DUMMY;
                int i11 = (c + 1 < d[1]) ? lst[1][c + 1] : DUMMY;
                int i20 = (c     < d[2]) ? lst[2][c]     : DUMMY;
                int i21 = (c + 1 < d[2]) ? lst[2][c + 1] : DUMMY;
                int i30 = (c     < d[3]) ? lst[3][c]     : DUMMY;
                int i31 = (c + 1 < d[3]) ? lst[3][c + 1] : DUMMY;
                float v00 = ld_dev(hp + i00 * S + s), v01 = ld_dev(hp + i01 * S + s);
                float v10 = ld_dev(hp + i10 * S + s), v11 = ld_dev(hp + i11 * S + s);
                float v20 = ld_dev(hp + i20 * S + s), v21 = ld_dev(hp + i21 * S + s);
                float v30 = ld_dev(hp + i30 * S + s), v31 = ld_dev(hp + i31 * S + s);
                a0 += v00 + v01; a1 += v10 + v11;
                a2 += v20 + v21; a3 += v30 + v31;
            }
            sAct[w][pp][0][s] = a0; sAct[w][pp][1][s] = a1;
            sAct[w][pp][2][s] = a2; sAct[w][pp][3][s] = a3;
            sH[w][pp][s] = hval;
            __syncthreads();                          // act/h scratch visible

            const float* actw = &sAct[w][pp][0][0];
            // ---- z and r gates (sequential, full 64-lane width: 2 nodes)
            const float z = fast_sigmoid(matvec(sW,        Uz, actw, &sH[w][pp][0], bzv, s));
            const float r = fast_sigmoid(matvec(sW + 4096, Ur, actw, &sH[w][pp][0], brv, s));
            sRH[w][pp][s] = r * hval;
            __syncthreads();                          // rh scratch visible

            // ---- hh and update
            const float hh   = fast_tanh(matvec(sW + 8192, Uh, actw, &sRH[w][pp][0], 0.f, s));
            const float hnew = fmaf(z, hval - hh, hh);         // z*h + (1-z)*hh
            st_dev(&hn[n * S + s], hnew);
            hval = hnew;

            const float* t = hp; hp = hn; hn = (float*)t;      // swap

            if (l != 2 || it != 4) { gbar(p.bar, phase, b); phase++; }
        }
    }

    // ---- epilogue in-register: node 5 = block 0, wave 2, half p==1
    if (b == 0 && w == 2 && pp == 1) {
        float y[5];
        #pragma unroll
        for (int j = 0; j < 5; ++j) y[j] = hval * p.ow[s * 5 + j];
        #pragma unroll
        for (int off = 1; off < 32; off <<= 1) {
            #pragma unroll
            for (int j = 0; j < 5; ++j) y[j] += __shfl_xor(y[j], off, 64);
        }
        #pragma unroll
        for (int j = 0; j < 5; ++j) y[j] += p.ob[j];
        float m = -1e30f;
        #pragma unroll
        for (int j = 0; j < 5; ++j) m = fmaxf(m, y[j]);
        float ssum = 0.f;
        #pragma unroll
        for (int j = 0; j < 5; ++j) ssum += __expf(y[j] - m);
        float lse = m + __logf(ssum);
        if (s < 5) p.out[s] = y[s] - lse;
    }
}

// ---------------------------------------------------------------------------
// Fallback chain — host launches it only if hipLaunchCooperativeKernel reports
// a synchronous rejection. Known-good round-3/5 structure.
// ---------------------------------------------------------------------------
__global__ __launch_bounds__(256) void init_h_fb(const float* __restrict__ x,
                                                 const float* __restrict__ fcw,
                                                 const float* __restrict__ fcb,
                                                 float* __restrict__ h0) {
    int t = blockIdx.x * 256 + threadIdx.x;
    int s = t & 31;
    int n = t >> 5;
    float acc = fcb[s];
    #pragma unroll 8
    for (int k = 0; k < FIN; ++k)
        acc = fmaf(x[n * FIN + k], fcw[k * S + s], acc);
    h0[n * S + s] = acc;
}

__global__ __launch_bounds__(512) void ggnn_iter_fb(
    const float* __restrict__ hprev, float* __restrict__ hnext,
    const int* __restrict__ deg, const int* __restrict__ csr,
    const float* __restrict__ wz, const float* __restrict__ wr, const float* __restrict__ wh,
    const float* __restrict__ uz, const float* __restrict__ ur, const float* __restrict__ uh,
    const float* __restrict__ bz, const float* __restrict__ br) {
    __shared__ __align__(16) float sWz[4096];
    __shared__ __align__(16) float sWr[4096];
    __shared__ __align__(16) float sWh[4096];
    __shared__ __align__(16) float sUz[1024], sUr[1024], sUh[1024];

    int tid = threadIdx.x;
    {
        float4*       dz = (float4*)sWz; const float4* gz = (const float4*)wz;
        float4*       dr = (float4*)sWr; const float4* gr = (const float4*)wr;
        float4*       dh = (float4*)sWh; const float4* gh = (const float4*)wh;
        for (int i = tid; i < 1024; i += 512) { dz[i] = gz[i]; dr[i] = gr[i]; dh[i] = gh[i]; }
        float4*       duz = (float4*)sUz; const float4* guz = (const float4*)uz;
        float4*       dur = (float4*)sUr; const float4* gur = (const float4*)ur;
        float4*       duh = (float4*)sUh; const float4* guh = (const float4*)uh;
        if (tid < 256) { duz[tid] = guz[tid]; dur[tid] = gur[tid]; duh[tid] = guh[tid]; }
    }
    __syncthreads();

    const int wid  = tid >> 6;
    const int lane = tid & 63;
    const int s    = lane & 31;
    const int g    = lane >> 5;
    const int n    = blockIdx.x * 8 + wid;

    const int d1 = min(deg[g * N + n], CAP);
    const int d2 = min(deg[(g + 2) * N + n], CAP);
    const int* __restrict__ l1 = csr + (g * N + n) * CAP;
    const int* __restrict__ l2 = csr + ((g + 2) * N + n) * CAP;
    float acc0 = 0.f, acc1 = 0.f;
    const int dmax = max(d1, d2);
    for (int i = 0; i < dmax; ++i) {
        if (i < d1) acc0 += hprev[l1[i] * S + s];
        if (i < d2) acc1 += hprev[l2[i] * S + s];
    }
    const float hval = hprev[n * S + s];

    const float* __restrict__ W1 = g ? sWr : sWz;
    const float* __restrict__ U1 = g ? sUr : sUz;
    float accA = g ? br[s] : bz[s];
    float accB = 0.f;
    float hA = 0.f, hB = 0.f;
    #pragma unroll
    for (int e = 0; e < E; ++e) {
        const float src = (e < 2) ? acc0 : acc1;
        const float* w1c = W1 + e * 1024 + s;
        const float* whc = sWh + e * 1024 + s;
        #pragma unroll
        for (int k = 0; k < 32; k += 2) {
            float a0 = rl(src, (e & 1) * 32 + k);
            float a1 = rl(src, (e & 1) * 32 + k + 1);
            accA = fmaf(a0, w1c[(k)     * 32], accA);
            accB = fmaf(a1, w1c[(k + 1) * 32], accB);
            hA   = fmaf(a0, whc[(k)     * 32], hA);
            hB   = fmaf(a1, whc[(k + 1) * 32], hB);
        }
    }
    #pragma unroll
    for (int k = 0; k < 32; k += 2) {
        accA = fmaf(rl(hval, k),     U1[(k)     * 32 + s], accA);
        accB = fmaf(rl(hval, k + 1), U1[(k + 1) * 32 + s], accB);
    }
    const float zr  = fast_sigmoid(accA + accB);
    const float r_s = __shfl(zr, 32 + s, 64);
    const float z_s = __shfl(zr, s, 64);
    const float rh  = r_s * hval;
    #pragma unroll
    for (int k = 0; k < 32; k += 2) {
        hA = fmaf(rl(rh, k),     sUh[(k)     * 32 + s], hA);
        hB = fmaf(rl(rh, k + 1), sUh[(k + 1) * 32 + s], hB);
    }
    const float hh = fast_tanh(hA + hB);
    const float hnew = fmaf(z_s, hval - hh, hh);
    if (g == 0) hnext[n * S + s] = hnew;
}

__global__ void epilogue_fb(const float* __restrict__ h,
                            const float* __restrict__ ow, const float* __restrict__ ob,
                            float* __restrict__ out) {
    int lane = threadIdx.x;
    float y = 0.f;
    if (lane < 5) {
        y = ob[lane];
        for (int k = 0; k < 32; ++k)
            y = fmaf(h[5 * S + k], ow[k * 5 + lane], y);
    }
    float m = -1e30f;
    #pragma unroll
    for (int j = 0; j < 5; ++j) m = fmaxf(m, __shfl(y, j, 64));
    float ssum = 0.f;
    #pragma unroll
    for (int j = 0; j < 5; ++j) ssum += __expf(__shfl(y, j, 64) - m);
    float lse = m + __logf(ssum);
    if (lane < 5) out[lane] = y - lse;
}

extern "C" void kernel_launch(void* const* d_in, const int* in_sizes, int n_in,
                              void* d_out, int out_size, void* d_ws, size_t ws_size,
                              hipStream_t stream) {
    const float* x     = (const float*)d_in[0];
    // d_in[1] = x_lengths (int32) — unused by the reference
    const float* edges = (const float*)d_in[2];
    const float* fcw   = (const float*)d_in[3];
    const float* fcb   = (const float*)d_in[4];
    const float* wz    = (const float*)d_in[5];
    const float* wr    = (const float*)d_in[6];
    const float* wh    = (const float*)d_in[7];
    const float* uz    = (const float*)d_in[8];
    const float* ur    = (const float*)d_in[9];
    const float* uh    = (const float*)d_in[10];
    const float* bz    = (const float*)d_in[11];
    const float* br    = (const float*)d_in[12];
    const float* ow    = (const float*)d_in[13];
    const float* ob    = (const float*)d_in[14];

    char* ws = (char*)d_ws;
    float* h0  = (float*)(ws);                   // 3073 rows * 32 * 4 = 393,344 B
    float* h1  = (float*)(ws + 393600);
    int*   deg = (int*)(ws + 787200);            // 49,152 B
    int*   bar = (int*)(ws + 836352);            // 2,048 B tree-barrier lines
    int*   csr = (int*)(ws + 838400);            // 3,145,728 B -> end 3,984,128

    hipMemsetAsync(deg, 0, 49152 + 2048, stream);
    build_csr<<<36864, 256, 0, stream>>>(edges, deg, csr);

    Params p;
    p.x = x; p.fcw = fcw; p.fcb = fcb;
    p.wz = wz; p.wr = wr; p.wh = wh;
    p.uz = uz; p.ur = ur; p.uh = uh;
    p.bz = bz; p.br = br; p.ow = ow; p.ob = ob;
    p.deg = deg; p.csr = csr; p.bar = bar;
    p.h0 = h0; p.h1 = h1; p.out = (float*)d_out;

    void* args[] = { &p };
    hipError_t err = hipLaunchCooperativeKernel((const void*)fused_ggnn,
                                                dim3(BLK), dim3(TPB), args, 0, stream);
    if (err != hipSuccess) {
        // Launch rejected synchronously -> known-good multi-dispatch path.
        init_h_fb<<<384, 256, 0, stream>>>(x, fcw, fcb, h0);
        float* ha = h0;
        float* hb = h1;
        for (int l = 0; l < 3; ++l) {
            for (int it = 0; it < 5; ++it) {
                ggnn_iter_fb<<<384, 512, 0, stream>>>(ha, hb, deg, csr,
                    wz + l * 4096, wr + l * 4096, wh + l * 4096,
                    uz + l * 1024, ur + l * 1024, uh + l * 1024,
                    bz + l * 32, br + l * 32);
                float* t = ha; ha = hb; hb = t;
            }
        }
        epilogue_fb<<<1, 64, 0, stream>>>(ha, ow, ob, (float*)d_out);
    }
}

// Round 10
// 477.986 us; speedup vs baseline: 1.1996x; 1.1996x over previous
//
#include <hip/hip_runtime.h>

constexpr int N     = 3072;
constexpr int S     = 32;
constexpr int E     = 4;
constexpr int FIN   = 64;
constexpr int CAP   = 64;     // max sources per (e,n); Binomial(3072,0.005) mean 15.4, P(>=64)~1e-19
constexpr int NNi   = N * N;  // 9,437,184
constexpr int DUMMY = N;      // extra all-zero h row for gather padding
constexpr int BLK   = 256;    // 1 block/CU
constexpr int TPB   = 768;    // 12 waves = 12 nodes per block; 256*12 = 3072
constexpr int NPB   = 12;
constexpr int PRE   = 16;     // preloaded indices per list (covers ~85% of degrees)

__device__ __forceinline__ float rl(float v, int lane) {   // wave-uniform broadcast via VALU
    return __int_as_float(__builtin_amdgcn_readlane(__float_as_int(v), lane));
}
__device__ __forceinline__ float fast_sigmoid(float x) {
    x = fminf(fmaxf(x, -30.f), 30.f);
    return 1.f / (1.f + __expf(-x));
}
__device__ __forceinline__ float fast_tanh(float x) {
    x = fminf(fmaxf(x, -15.f), 15.f);
    float e = __expf(2.f * x);
    return (e - 1.f) / (e + 1.f);
}

// Cache-bypassing accessors: relaxed AGENT-scope atomics are coherent at the
// memory-side Infinity Cache (above the non-coherent per-XCD L2s).
__device__ __forceinline__ float ld_dev(const float* p) {
    return __hip_atomic_load((float*)p, __ATOMIC_RELAXED, __HIP_MEMORY_SCOPE_AGENT);
}
__device__ __forceinline__ void st_dev(float* p, float v) {
    __hip_atomic_store(p, v, __ATOMIC_RELAXED, __HIP_MEMORY_SCOPE_AGENT);
}

// Two-level monotone tree barrier (reset-free), 16 groups x 16 blocks.
__device__ __forceinline__ void gbar(int* bar, int ph, int b) {
    __syncthreads();          // compiler drains vmcnt(0) before s_barrier
    if (threadIdx.x == 0) {
        int* grp  = bar + (b >> 4) * 16;
        int* root = bar + 256;
        int* go   = bar + 272;
        int old = __hip_atomic_fetch_add(grp, 1, __ATOMIC_RELAXED, __HIP_MEMORY_SCOPE_AGENT);
        if (old + 1 == ph * 16) {
            int old2 = __hip_atomic_fetch_add(root, 1, __ATOMIC_RELAXED, __HIP_MEMORY_SCOPE_AGENT);
            if (old2 + 1 == ph * 16)
                __hip_atomic_store(go, ph, __ATOMIC_RELAXED, __HIP_MEMORY_SCOPE_AGENT);
        }
        int spins = 0;
        while (__hip_atomic_load(go, __ATOMIC_RELAXED, __HIP_MEMORY_SCOPE_AGENT) < ph) {
            __builtin_amdgcn_s_sleep(2);
            if (++spins > 300000) break;           // wedge -> terminate, not hang
        }
    }
    __syncthreads();
}

// ---------------------------------------------------------------------------
// Pass 1 (separate dispatch; inter-dispatch flush makes results coherent):
// dense fp32 adjacency -> CSR (per (e, target n): list of sources m).
// ---------------------------------------------------------------------------
__global__ __launch_bounds__(256) void build_csr(const float* __restrict__ edges,
                                                 int* __restrict__ deg,
                                                 int* __restrict__ csr) {
    int t = blockIdx.x * 256 + threadIdx.x;
    int idx4 = t * 4;
    float4 v = *reinterpret_cast<const float4*>(edges + idx4);
    if (v.x == 0.f && v.y == 0.f && v.z == 0.f && v.w == 0.f) return;
    int e   = idx4 / NNi;
    int rem = idx4 - e * NNi;
    int m   = rem / N;
    int nb  = rem - m * N;
    float w[4] = {v.x, v.y, v.z, v.w};
    int base = e * N + nb;
    #pragma unroll
    for (int j = 0; j < 4; ++j) {
        if (w[j] != 0.f) {
            int slot = base + j;
            int pos = atomicAdd(&deg[slot], 1);
            if (pos < CAP) csr[slot * CAP + pos] = m;
        }
    }
}

struct Params {
    const float *x, *fcw, *fcb;
    const float *wz, *wr, *wh, *uz, *ur, *uh, *bz, *br;
    const float *ow, *ob;
    const int   *deg, *csr;
    int   *bar;
    float *h0, *h1, *out;
};

// ---------------------------------------------------------------------------
// Fused cooperative kernel (round-8 structure + burst gather + register hval).
// One wave per node; lane = (g,s); half g handles edge types {g, g+2}.
// LDS 61.7 KB -> 1 block/CU at TPB=768 (12 waves); launch_bounds(768,3)
// caps VGPR at ~170 so the 12-wave block always fits.
// ---------------------------------------------------------------------------
__global__ __launch_bounds__(TPB, 3) void fused_ggnn(Params p) {
    __shared__ __align__(16) float sW[3 * 4096];   // [z|r|h][e][k][s]
    __shared__ __align__(16) float sU[3 * 1024];   // [z|r|h][k][s]
    __shared__ float sB[64];                       // [bz|br][s]

    const int tid  = threadIdx.x;
    const int b    = blockIdx.x;
    const int wid  = tid >> 6;
    const int lane = tid & 63;
    const int s    = lane & 31;
    const int g    = lane >> 5;
    const int n    = b * NPB + wid;

    // ---- init: h0 = x @ fc_w + fc_b, computed redundantly in both halves so
    // hval lives in a register for the whole kernel; store once (g==0).
    float hval;
    {
        float acc = p.fcb[s];
        #pragma unroll 8
        for (int k = 0; k < FIN; ++k)
            acc = fmaf(p.x[n * FIN + k], p.fcw[k * S + s], acc);
        hval = acc;
        if (g == 0) st_dev(&p.h0[n * S + s], acc);
    }
    if (b == 0) {                                  // zero dummy rows, both buffers
        if (tid < 32)      st_dev(&p.h0[DUMMY * S + tid], 0.f);
        else if (tid < 64) st_dev(&p.h1[DUMMY * S + (tid - 32)], 0.f);
    }

    // ---- iteration-invariant CSR state (prev-dispatch data: cached reads OK)
    const int slot1 = g * N + n;
    const int slot2 = (g + 2) * N + n;
    const int d1 = min(p.deg[slot1], CAP);
    const int d2 = min(p.deg[slot2], CAP);
    const int* __restrict__ l1 = p.csr + slot1 * CAP;
    const int* __restrict__ l2 = p.csr + slot2 * CAP;
    const int dm = max(d1, d2);

    // Preload first PRE indices per list with predication resolved ONCE.
    // These are iteration-invariant -> the hot gather has zero index loads.
    int pi[PRE], qi[PRE];
    #pragma unroll
    for (int c = 0; c < PRE; ++c) {
        pi[c] = (c < d1) ? l1[c] : DUMMY;
        qi[c] = (c < d2) ? l2[c] : DUMMY;
    }

    const float* hp = p.h0;
    float*       hn = p.h1;
    int phase = 1;
    gbar(p.bar, phase, b); phase++;                // h0 device-visible

    for (int l = 0; l < 3; ++l) {
        __syncthreads();                           // guard LDS reuse across layers
        {
            float4* dw = (float4*)sW;
            const float4* gz = (const float4*)(p.wz + l * 4096);
            const float4* gr = (const float4*)(p.wr + l * 4096);
            const float4* gh = (const float4*)(p.wh + l * 4096);
            for (int i = tid; i < 1024; i += TPB) {
                dw[i] = gz[i]; dw[1024 + i] = gr[i]; dw[2048 + i] = gh[i];
            }
            float4* du = (float4*)sU;
            const float4* guz = (const float4*)(p.uz + l * 1024);
            const float4* gur = (const float4*)(p.ur + l * 1024);
            const float4* guh = (const float4*)(p.uh + l * 1024);
            if (tid < 256) {
                du[tid] = guz[tid]; du[256 + tid] = gur[tid]; du[512 + tid] = guh[tid];
            }
            if (tid < 64) sB[tid] = (tid < 32) ? p.bz[l * 32 + tid]
                                               : p.br[l * 32 + (tid - 32)];
        }
        __syncthreads();

        for (int it = 0; it < 5; ++it) {
            // ---- phase A: burst gather — 32 independent bypass loads in
            // flight (fully unrolled, register indices, no predication).
            float acc0 = 0.f, acc1 = 0.f;
            #pragma unroll
            for (int c = 0; c < PRE; c += 4) {
                float x0 = ld_dev(hp + pi[c + 0] * S + s);
                float x1 = ld_dev(hp + pi[c + 1] * S + s);
                float x2 = ld_dev(hp + pi[c + 2] * S + s);
                float x3 = ld_dev(hp + pi[c + 3] * S + s);
                float y0 = ld_dev(hp + qi[c + 0] * S + s);
                float y1 = ld_dev(hp + qi[c + 1] * S + s);
                float y2 = ld_dev(hp + qi[c + 2] * S + s);
                float y3 = ld_dev(hp + qi[c + 3] * S + s);
                acc0 += (x0 + x1) + (x2 + x3);
                acc1 += (y0 + y1) + (y2 + y3);
            }
            // rare tail: degree > PRE (wave-uniform condition per half)
            for (int c = PRE; c < dm; c += 4) {
                int r0 = (c + 0 < d1) ? l1[c + 0] : DUMMY;
                int r1 = (c + 1 < d1) ? l1[c + 1] : DUMMY;
                int r2 = (c + 2 < d1) ? l1[c + 2] : DUMMY;
                int r3 = (c + 3 < d1) ? l1[c + 3] : DUMMY;
                int t0 = (c + 0 < d2) ? l2[c + 0] : DUMMY;
                int t1 = (c + 1 < d2) ? l2[c + 1] : DUMMY;
                int t2 = (c + 2 < d2) ? l2[c + 2] : DUMMY;
                int t3 = (c + 3 < d2) ? l2[c + 3] : DUMMY;
                acc0 += (ld_dev(hp + r0 * S + s) + ld_dev(hp + r1 * S + s))
                      + (ld_dev(hp + r2 * S + s) + ld_dev(hp + r3 * S + s));
                acc1 += (ld_dev(hp + t0 * S + s) + ld_dev(hp + t1 * S + s))
                      + (ld_dev(hp + t2 * S + s) + ld_dev(hp + t3 * S + s));
            }

            // ---- phases B+C: z|r gate (split across wave halves) + hh
            const float* __restrict__ W1 = g ? (sW + 4096) : sW;
            const float* __restrict__ U1 = g ? (sU + 1024) : sU;
            const float* __restrict__ Wh = sW + 8192;
            float accA = sB[g * 32 + s];
            float accB = 0.f;
            float hA = 0.f, hB = 0.f;
            #pragma unroll
            for (int e = 0; e < E; ++e) {
                const float src = (e < 2) ? acc0 : acc1;
                const float* w1c = W1 + e * 1024 + s;
                const float* whc = Wh + e * 1024 + s;
                #pragma unroll
                for (int k = 0; k < 32; k += 2) {
                    float a0 = rl(src, (e & 1) * 32 + k);
                    float a1 = rl(src, (e & 1) * 32 + k + 1);
                    accA = fmaf(a0, w1c[(k)     * 32], accA);
                    accB = fmaf(a1, w1c[(k + 1) * 32], accB);
                    hA   = fmaf(a0, whc[(k)     * 32], hA);
                    hB   = fmaf(a1, whc[(k + 1) * 32], hB);
                }
            }
            #pragma unroll
            for (int k = 0; k < 32; k += 2) {
                accA = fmaf(rl(hval, k),     U1[(k)     * 32 + s], accA);
                accB = fmaf(rl(hval, k + 1), U1[(k + 1) * 32 + s], accB);
            }
            const float zr  = fast_sigmoid(accA + accB);   // z (g=0) | r (g=1)
            const float r_s = __shfl(zr, 32 + s, 64);
            const float z_s = __shfl(zr, s, 64);
            const float rh  = r_s * hval;
            const float* __restrict__ Uh = sU + 2048;
            #pragma unroll
            for (int k = 0; k < 32; k += 2) {
                hA = fmaf(rl(rh, k),     Uh[(k)     * 32 + s], hA);
                hB = fmaf(rl(rh, k + 1), Uh[(k + 1) * 32 + s], hB);
            }
            const float hh   = fast_tanh(hA + hB);
            const float hnew = fmaf(z_s, hval - hh, hh);   // z*h + (1-z)*hh
            if (g == 0) st_dev(&hn[n * S + s], hnew);
            hval = hnew;                                   // identical in both halves

            const float* t = hp; hp = hn; hn = (float*)t;  // swap

            if (l != 2 || it != 4) {                       // no barrier after last iter
                gbar(p.bar, phase, b); phase++;
            }
        }
    }

    // ---- epilogue in-register: node 5 = block 0, wave 5 (hval holds final h)
    if (b == 0 && wid == 5) {
        float y[5];
        #pragma unroll
        for (int j = 0; j < 5; ++j) y[j] = hval * p.ow[s * 5 + j];
        #pragma unroll
        for (int off = 1; off < 32; off <<= 1) {
            #pragma unroll
            for (int j = 0; j < 5; ++j) y[j] += __shfl_xor(y[j], off, 64);
        }
        #pragma unroll
        for (int j = 0; j < 5; ++j) y[j] += p.ob[j];
        float m = -1e30f;
        #pragma unroll
        for (int j = 0; j < 5; ++j) m = fmaxf(m, y[j]);
        float ssum = 0.f;
        #pragma unroll
        for (int j = 0; j < 5; ++j) ssum += __expf(y[j] - m);
        float lse = m + __logf(ssum);
        #pragma unroll
        for (int j = 0; j < 5; ++j) if (lane == j) p.out[j] = y[j] - lse;
    }
}

// ---------------------------------------------------------------------------
// Fallback chain — host launches it only if hipLaunchCooperativeKernel reports
// a synchronous rejection. Known-good round-3/5 structure.
// ---------------------------------------------------------------------------
__global__ __launch_bounds__(256) void init_h_fb(const float* __restrict__ x,
                                                 const float* __restrict__ fcw,
                                                 const float* __restrict__ fcb,
                                                 float* __restrict__ h0) {
    int t = blockIdx.x * 256 + threadIdx.x;
    int s = t & 31;
    int n = t >> 5;
    float acc = fcb[s];
    #pragma unroll 8
    for (int k = 0; k < FIN; ++k)
        acc = fmaf(x[n * FIN + k], fcw[k * S + s], acc);
    h0[n * S + s] = acc;
}

__global__ __launch_bounds__(512) void ggnn_iter_fb(
    const float* __restrict__ hprev, float* __restrict__ hnext,
    const int* __restrict__ deg, const int* __restrict__ csr,
    const float* __restrict__ wz, const float* __restrict__ wr, const float* __restrict__ wh,
    const float* __restrict__ uz, const float* __restrict__ ur, const float* __restrict__ uh,
    const float* __restrict__ bz, const float* __restrict__ br) {
    __shared__ __align__(16) float sWz[4096];
    __shared__ __align__(16) float sWr[4096];
    __shared__ __align__(16) float sWh[4096];
    __shared__ __align__(16) float sUz[1024], sUr[1024], sUh[1024];

    int tid = threadIdx.x;
    {
        float4*       dz = (float4*)sWz; const float4* gz = (const float4*)wz;
        float4*       dr = (float4*)sWr; const float4* gr = (const float4*)wr;
        float4*       dh = (float4*)sWh; const float4* gh = (const float4*)wh;
        for (int i = tid; i < 1024; i += 512) { dz[i] = gz[i]; dr[i] = gr[i]; dh[i] = gh[i]; }
        float4*       duz = (float4*)sUz; const float4* guz = (const float4*)uz;
        float4*       dur = (float4*)sUr; const float4* gur = (const float4*)ur;
        float4*       duh = (float4*)sUh; const float4* guh = (const float4*)uh;
        if (tid < 256) { duz[tid] = guz[tid]; dur[tid] = gur[tid]; duh[tid] = guh[tid]; }
    }
    __syncthreads();

    const int wid  = tid >> 6;
    const int lane = tid & 63;
    const int s    = lane & 31;
    const int g    = lane >> 5;
    const int n    = blockIdx.x * 8 + wid;

    const int d1 = min(deg[g * N + n], CAP);
    const int d2 = min(deg[(g + 2) * N + n], CAP);
    const int* __restrict__ l1 = csr + (g * N + n) * CAP;
    const int* __restrict__ l2 = csr + ((g + 2) * N + n) * CAP;
    float acc0 = 0.f, acc1 = 0.f;
    const int dmax = max(d1, d2);
    for (int i = 0; i < dmax; ++i) {
        if (i < d1) acc0 += hprev[l1[i] * S + s];
        if (i < d2) acc1 += hprev[l2[i] * S + s];
    }
    const float hval = hprev[n * S + s];

    const float* __restrict__ W1 = g ? sWr : sWz;
    const float* __restrict__ U1 = g ? sUr : sUz;
    float accA = g ? br[s] : bz[s];
    float accB = 0.f;
    float hA = 0.f, hB = 0.f;
    #pragma unroll
    for (int e = 0; e < E; ++e) {
        const float src = (e < 2) ? acc0 : acc1;
        const float* w1c = W1 + e * 1024 + s;
        const float* whc = sWh + e * 1024 + s;
        #pragma unroll
        for (int k = 0; k < 32; k += 2) {
            float a0 = rl(src, (e & 1) * 32 + k);
            float a1 = rl(src, (e & 1) * 32 + k + 1);
            accA = fmaf(a0, w1c[(k)     * 32], accA);
            accB = fmaf(a1, w1c[(k + 1) * 32], accB);
            hA   = fmaf(a0, whc[(k)     * 32], hA);
            hB   = fmaf(a1, whc[(k + 1) * 32], hB);
        }
    }
    #pragma unroll
    for (int k = 0; k < 32; k += 2) {
        accA = fmaf(rl(hval, k),     U1[(k)     * 32 + s], accA);
        accB = fmaf(rl(hval, k + 1), U1[(k + 1) * 32 + s], accB);
    }
    const float zr  = fast_sigmoid(accA + accB);
    const float r_s = __shfl(zr, 32 + s, 64);
    const float z_s = __shfl(zr, s, 64);
    const float rh  = r_s * hval;
    #pragma unroll
    for (int k = 0; k < 32; k += 2) {
        hA = fmaf(rl(rh, k),     sUh[(k)     * 32 + s], hA);
        hB = fmaf(rl(rh, k + 1), sUh[(k + 1) * 32 + s], hB);
    }
    const float hh = fast_tanh(hA + hB);
    const float hnew = fmaf(z_s, hval - hh, hh);
    if (g == 0) hnext[n * S + s] = hnew;
}

__global__ void epilogue_fb(const float* __restrict__ h,
                            const float* __restrict__ ow, const float* __restrict__ ob,
                            float* __restrict__ out) {
    int lane = threadIdx.x;
    float y = 0.f;
    if (lane < 5) {
        y = ob[lane];
        for (int k = 0; k < 32; ++k)
            y = fmaf(h[5 * S + k], ow[k * 5 + lane], y);
    }
    float m = -1e30f;
    #pragma unroll
    for (int j = 0; j < 5; ++j) m = fmaxf(m, __shfl(y, j, 64));
    float ssum = 0.f;
    #pragma unroll
    for (int j = 0; j < 5; ++j) ssum += __expf(__shfl(y, j, 64) - m);
    float lse = m + __logf(ssum);
    if (lane < 5) out[lane] = y - lse;
}

extern "C" void kernel_launch(void* const* d_in, const int* in_sizes, int n_in,
                              void* d_out, int out_size, void* d_ws, size_t ws_size,
                              hipStream_t stream) {
    const float* x     = (const float*)d_in[0];
    // d_in[1] = x_lengths (int32) — unused by the reference
    const float* edges = (const float*)d_in[2];
    const float* fcw   = (const float*)d_in[3];
    const float* fcb   = (const float*)d_in[4];
    const float* wz    = (const float*)d_in[5];
    const float* wr    = (const float*)d_in[6];
    const float* wh    = (const float*)d_in[7];
    const float* uz    = (const float*)d_in[8];
    const float* ur    = (const float*)d_in[9];
    const float* uh    = (const float*)d_in[10];
    const float* bz    = (const float*)d_in[11];
    const float* br    = (const float*)d_in[12];
    const float* ow    = (const float*)d_in[13];
    const float* ob    = (const float*)d_in[14];

    char* ws = (char*)d_ws;
    float* h0  = (float*)(ws);                   // 3073 rows * 32 * 4 = 393,344 B
    float* h1  = (float*)(ws + 393600);
    int*   deg = (int*)(ws + 787200);            // 49,152 B
    int*   bar = (int*)(ws + 836352);            // 2,048 B tree-barrier lines
    int*   csr = (int*)(ws + 838400);            // 3,145,728 B -> end 3,984,128

    hipMemsetAsync(deg, 0, 49152 + 2048, stream);
    build_csr<<<36864, 256, 0, stream>>>(edges, deg, csr);

    Params p;
    p.x = x; p.fcw = fcw; p.fcb = fcb;
    p.wz = wz; p.wr = wr; p.wh = wh;
    p.uz = uz; p.ur = ur; p.uh = uh;
    p.bz = bz; p.br = br; p.ow = ow; p.ob = ob;
    p.deg = deg; p.csr = csr; p.bar = bar;
    p.h0 = h0; p.h1 = h1; p.out = (float*)d_out;

    void* args[] = { &p };
    hipError_t err = hipLaunchCooperativeKernel((const void*)fused_ggnn,
                                                dim3(BLK), dim3(TPB), args, 0, stream);
    if (err != hipSuccess) {
        // Launch rejected synchronously -> known-good multi-dispatch path.
        init_h_fb<<<384, 256, 0, stream>>>(x, fcw, fcb, h0);
        float* ha = h0;
        float* hb = h1;
        for (int l = 0; l < 3; ++l) {
            for (int it = 0; it < 5; ++it) {
                ggnn_iter_fb<<<384, 512, 0, stream>>>(ha, hb, deg, csr,
                    wz + l * 4096, wr + l * 4096, wh + l * 4096,
                    uz + l * 1024, ur + l * 1024, uh + l * 1024,
                    bz + l * 32, br + l * 32);
                float* t = ha; ha = hb; hb = t;
            }
        }
        epilogue_fb<<<1, 64, 0, stream>>>(ha, ow, ob, (float*)d_out);
    }
}